// Round 6
// baseline (609.832 us; speedup 1.0000x reference)
//
#include <hip/hip_runtime.h>

// uDTW forward DP, R5: wave-boundary values in SGPRs (readfirstlane).
// R2-R4 post-mortem: VGPR_Count=52 < live set (~64+) => the nbv[16] burst
// preload never lived in VGPRs; compiler re-read it (LDS/scratch) inside the
// unrolled step loop, putting a ~120-400cyc waitcnt ON the serial DP chain
// every step. Fix: the edge reads are wave-uniform, so move them to SGPRs via
// readfirstlane at burst-preload time. Step body then has ZERO memory ops on
// the chain: exp2 -> dpp -> cndmask(sgpr) -> add -> rcp -> fma -> exp2.
// Also: carry D pre-scaled by -log2(e) (one less mul on the chain tail).
// Structure otherwise = R4 (producer->consumer spin, write-once edge array).

constexpr int N = 512;
constexpr int M = 512;
constexpr int BATCH = 32;
constexpr int NM = N + M;                  // 1024; diags d = 2..NM
constexpr int K = 16;                      // diagonals per burst
constexpr int NB = 64;                     // bursts cover d = 2..1025
constexpr float NL2E = -1.4426950408889634f;   // -log2(e)
constexpr float NLN2 = -0.6931471805599453f;   // -ln(2) = 1/NL2E

__device__ __forceinline__ float lane_shr1(float x) {
  // lane n gets lane n-1's x; lane 0 gets 0 (overridden by caller).
  return __int_as_float(
      __builtin_amdgcn_update_dpp(0, __float_as_int(x), 0x138, 0xf, 0xf, true));
}

__global__ __launch_bounds__(512, 2)
void softdtw_fwd(const float* __restrict__ D,
                 const float* __restrict__ Sig,
                 float* __restrict__ out) {
  const int b = blockIdx.x;
  const int t = threadIdx.x;           // row r = t, cell i = t+1
  const int w = t >> 6;                // wave 0..7
  const int lane = t & 63;
  const bool l0 = (lane == 0);
  const float* Drow = D + ((size_t)b * N + t) * M;

  // Write-once boundary data: edge[w][c] = (exp(-R), Ddiag*NL2E) of row 64w+63
  // at its column c (diag d = 64w + 65 + c). Waves 0..6 publish, 1..7 read.
  __shared__ float2 edge[7][512];
  __shared__ volatile int prog[8];     // bursts completed per wave (monotone)
  if (t < 8) prog[t] = 0;

  // rolling window of my D row, prefetch depth 5
  float4 Q0 = *(const float4*)(Drow + 0);
  float4 Q1 = *(const float4*)(Drow + 4);
  float4 Q2 = *(const float4*)(Drow + 8);
  float4 Q3 = *(const float4*)(Drow + 12);
  float4 Q4 = *(const float4*)(Drow + 16);

  // carried state (D pre-scaled by NL2E): own cell at d-1, nbr (i-1) at d-2
  float eSelf = 0.f, dSelfL = 0.f;                 // exp(-R[i,d-1]), NL2E*Ddiag
  float eN2 = (t == 0) ? 1.f : 0.f, dN2L = 0.f;    // exp(-R[i-1,d-2]) (R[0,0]=0)

  // Sig contributes only via 4 elements at the final cell
  float sgA = 0.f, sg0 = 0.f, sg1 = 0.f, sg2 = 0.f;
  if (t == N - 1) {
    const float* Sb = Sig + (size_t)b * N * M;
    sgA = Sb[(size_t)(N - 1) * M + (M - 1)];
    sg0 = Sb[(size_t)(N - 2) * M + (M - 2)];
    sg1 = Sb[(size_t)(N - 2) * M + (M - 1)];
    sg2 = Sb[(size_t)(N - 1) * M + (M - 2)];
  }
  __syncthreads();                     // the ONLY block-wide barrier (init)

  // burst B covers diags [2+16B, 17+16B]; wave w active for B in [4w, 4w+35].
  const int Bl = 4 * w;
  const int Bh = 4 * w + 35;

  for (int B = 0; B < NB; ++B) {
    const bool active = (B >= Bl) && (B <= Bh);
    if (active) {
      if (w > 0) {
        while (prog[w - 1] < B + 1) __builtin_amdgcn_s_sleep(1);
        __threadfence_block();         // acquire: order edge reads below
      }
      const int d0 = 2 + B * K;
      // neighbor boundary values for diags d0-1 .. d0+K-2, held in SGPRS.
      // producer (w-1) stored diag dp at index dp - 64w - 1.
      int nbE[K], nbD[K];              // bit patterns, wave-uniform -> SGPR
      if (w > 0) {
        const int sbase = d0 - 2 - 64 * w;   // index for k=0 (diag d0-1)
        #pragma unroll
        for (int k = 0; k < K; ++k) {
          int s = sbase + k;
          int sc = s < 0 ? 0 : (s > 511 ? 511 : s);
          float2 v = edge[w - 1][sc];
          bool inr = (s >= 0) && (s <= 511);
          nbE[k] = __builtin_amdgcn_readfirstlane(
                       inr ? __float_as_int(v.x) : 0);
          nbD[k] = __builtin_amdgcn_readfirstlane(
                       inr ? __float_as_int(v.y) : 0);
        }
      } else {
        #pragma unroll
        for (int k = 0; k < K; ++k) { nbE[k] = 0; nbD[k] = 0; }
      }
      #pragma unroll
      for (int k = 0; k < K; ++k) {
        const int d = d0 + k;
        const int c = d - t - 2;        // my column this step (j = c+1)
        const bool valid = (c >= 0) && (c < M);
        // my D diagonal value, pre-scaled (0 outside matrix)
        float dddL = 0.f;
        {
          const int ph = c & 3;
          float v = (ph == 0) ? Q0.x : (ph == 1) ? Q0.y : (ph == 2) ? Q0.z : Q0.w;
          if (valid) dddL = v * NL2E;
          if (c >= 0 && ph == 3 && c < M - 1) {
            Q0 = Q1; Q1 = Q2; Q2 = Q3; Q3 = Q4;
            int cb = c + 17; if (cb > M - 4) cb = M - 4;
            Q4 = *(const float4*)(Drow + cb);
          }
        }
        // neighbor (i-1) at diag d-1: in-wave via DPP, wave boundary via SGPR
        float sE = lane_shr1(eSelf);
        float sD = lane_shr1(dSelfL);
        if (l0) { sE = __int_as_float(nbE[k]); sD = __int_as_float(nbD[k]); }
        const float e0 = eN2, e1 = sE, e2 = eSelf;
        const float sum = (e0 + e2) + e1;
        const float inv = __builtin_amdgcn_rcpf(sum);
        const float numL = fmaf(e0, dN2L, fmaf(e1, sD, e2 * dSelfL));
        const float r2   = fmaf(inv, numL, dddL);   // = -log2e*(ddd+inv*num)
        float newE = __builtin_amdgcn_exp2f(r2);
        newE = valid ? newE : 0.f;      // masks NaN from sum==0 (rcp(0)=inf)
        if (d == NM && t == N - 1) {    // final cell (512,512)
          out[b] = r2 * NLN2;                                           // rlast
          out[BATCH + b] = sgA + inv * (e0 * sg0 + e1 * sg1 + e2 * sg2); // slast
        }
        // rotate carries; publish boundary (write-once: index = my column c)
        eN2 = e1; dN2L = sD;
        eSelf = newE; dSelfL = dddL;
        if (lane == 63 && w < 7 && valid)
          edge[w][c] = make_float2(newE, dddL);
      }
      __threadfence_block();           // release: edges before flag bump
    }
    if (lane == 63) prog[w] = B + 1;   // monotone progress
  }
}

extern "C" void kernel_launch(void* const* d_in, const int* in_sizes, int n_in,
                              void* d_out, int out_size, void* d_ws, size_t ws_size,
                              hipStream_t stream) {
  const float* D   = (const float*)d_in[0];
  const float* Sig = (const float*)d_in[1];
  float* out = (float*)d_out;
  softdtw_fwd<<<dim3(BATCH), dim3(512), 0, stream>>>(D, Sig, out);
}

// Round 7
// 197.715 us; speedup vs baseline: 3.0844x; 3.0844x over previous
//
#include <hip/hip_runtime.h>

// uDTW forward DP, R6: R3 phase-barrier skeleton + register-resident preloads.
// R3-R5 post-mortem: VGPR_Count stuck at 52 < live set (>=64) => burst
// preloads (nbv[16], and the D window) were re-read from LDS/memory INSIDE the
// 16-step loop, putting lgkmcnt waits on the serial chain. Fixes:
//  - neighbor boundary preload as 8 NAMED float4 (n0..n7), constant-index use
//  - D values for the burst as 16 NAMED floats (g0..g15), built once/burst by
//    a 2-stage funnel shift from 5 raw float4 loads (kills the per-step phase
//    select AND the divergent Q-rotate block)
//  - publish: unconditional all-lane ds_write_b64 into a write-once edge
//    array with +-64-col halos (lane 63's write is provably last per column;
//    invalid writes land as (0,0) = virtual-pad semantics) — no exec masking
//  - waves skip bursts with no valid cells (B in [4w, 4w+35] only)
// Cell math identical to R3/R5 (absmax 0.0). exp(-R) in [e^-2, 1] for valid
// preds (R = D + convex-comb of D's <= 2), so no max-subtraction needed.

constexpr int N = 512;
constexpr int M = 512;
constexpr int BATCH = 32;
constexpr int NM = N + M;                  // 1024; diags d = 2..NM
constexpr int K = 16;                      // diagonals per burst
constexpr int NB = 64;                     // bursts cover d = 2..1025
constexpr int PHASES = NB + 7;             // 71
constexpr float NL2E = -1.4426950408889634f;   // -log2(e)
constexpr float NLN2 = -0.6931471805599453f;   // -ln(2)

__device__ __forceinline__ float lane_shr1(float x) {
  // lane n gets lane n-1's x; lane 0 gets 0 (overridden by caller).
  return __int_as_float(
      __builtin_amdgcn_update_dpp(0, __float_as_int(x), 0x138, 0xf, 0xf, true));
}

__global__ __launch_bounds__(512, 2)
void softdtw_fwd(const float* __restrict__ D,
                 const float* __restrict__ Sig,
                 float* __restrict__ out) {
  const int b = blockIdx.x;
  const int t = threadIdx.x;           // row r = t, cell i = t+1
  const int w = t >> 6;                // wave 0..7
  const int lane = t & 63;
  const bool l0 = (lane == 0);
  const float4* Drow4 = (const float4*)(D + ((size_t)b * N + t) * M);

  // edge[w][64 + c] = (exp(-R), NL2E*Ddiag) of row 64w+63 at column c.
  // c in [-64, 576): halos are never read as live data and stay (0,0).
  __shared__ float2 edge[8][640];
  for (int idx = t; idx < 8 * 640; idx += 512)
    ((float2*)edge)[idx] = make_float2(0.f, 0.f);

  // carried state: own cell at d-1, neighbor (i-1) at d-2 (D pre-scaled)
  float eSelf = 0.f, dSelfL = 0.f;
  float eN2 = (t == 0) ? 1.f : 0.f, dN2L = 0.f;   // R[0,0]=0 -> e=1

  // Sig contributes only via 4 elements at the final cell
  float sgA = 0.f, sg0 = 0.f, sg1 = 0.f, sg2 = 0.f;
  if (t == N - 1) {
    const float* Sb = Sig + (size_t)b * N * M;
    sgA = Sb[(size_t)(N - 1) * M + (M - 1)];
    sg0 = Sb[(size_t)(N - 2) * M + (M - 2)];
    sg1 = Sb[(size_t)(N - 2) * M + (M - 1)];
    sg2 = Sb[(size_t)(N - 1) * M + (M - 2)];
  }
  __syncthreads();

  const int Bl = 4 * w;                // first burst with any valid cell
  const int Bh = 4 * w + 35;           // last

  for (int p = 0; p < PHASES; ++p) {
    const int B = p - w;
    if (B >= Bl && B <= Bh) {
      const int d0 = 2 + B * K;
      const int c0 = d0 - t - 2;       // my column at k=0; in [-63, 560]

      // ---- raw D loads: 5 quads covering floats [4*(c0>>2), +20)
      const int q0 = c0 >> 2;          // arithmetic shift = floor
      int qa = min(max(q0 + 0, 0), 127);
      int qb = min(max(q0 + 1, 0), 127);
      int qc = min(max(q0 + 2, 0), 127);
      int qd = min(max(q0 + 3, 0), 127);
      int qe = min(max(q0 + 4, 0), 127);
      float4 r0 = Drow4[qa], r1 = Drow4[qb], r2q = Drow4[qc],
             r3 = Drow4[qd], r4 = Drow4[qe];
      // clamp artifacts only affect elements with c outside [0,512) -> masked.

      // ---- funnel align by s = c0 & 3: g_e = D[c0 + e]
      const int s = c0 & 3;
      const bool s2 = (s & 2) != 0, s1b = (s & 1) != 0;
      float x0  = s2 ? r0.z  : r0.x,  x1  = s2 ? r0.w  : r0.y,
            x2  = s2 ? r1.x  : r0.z,  x3  = s2 ? r1.y  : r0.w,
            x4  = s2 ? r1.z  : r1.x,  x5  = s2 ? r1.w  : r1.y,
            x6  = s2 ? r2q.x : r1.z,  x7  = s2 ? r2q.y : r1.w,
            x8  = s2 ? r2q.z : r2q.x, x9  = s2 ? r2q.w : r2q.y,
            x10 = s2 ? r3.x  : r2q.z, x11 = s2 ? r3.y  : r2q.w,
            x12 = s2 ? r3.z  : r3.x,  x13 = s2 ? r3.w  : r3.y,
            x14 = s2 ? r4.x  : r3.z,  x15 = s2 ? r4.y  : r3.w,
            x16 = s2 ? r4.z  : r4.x,  x17 = s2 ? r4.w  : r4.y;
      float g0  = s1b ? x1  : x0,  g1  = s1b ? x2  : x1,
            g2  = s1b ? x3  : x2,  g3  = s1b ? x4  : x3,
            g4  = s1b ? x5  : x4,  g5  = s1b ? x6  : x5,
            g6  = s1b ? x7  : x6,  g7  = s1b ? x8  : x7,
            g8  = s1b ? x9  : x8,  g9  = s1b ? x10 : x9,
            g10 = s1b ? x11 : x10, g11 = s1b ? x12 : x11,
            g12 = s1b ? x13 : x12, g13 = s1b ? x14 : x13,
            g14 = s1b ? x15 : x14, g15 = s1b ? x16 : x15;

      // ---- neighbor boundary preload: 8 named float4 (16 (E,D) pairs).
      // producer col for my diag d is cp = d - 64w - 2; base cp0 = d0-64w-2
      float4 n0, n1, n2, n3, n4, n5, n6, n7;
      if (w > 0) {
        const int cp0 = d0 - 64 * w - 2;          // even, in [0, 560]
        const float4* ep = (const float4*)&edge[w - 1][64 + cp0];
        n0 = ep[0]; n1 = ep[1]; n2 = ep[2]; n3 = ep[3];
        n4 = ep[4]; n5 = ep[5]; n6 = ep[6]; n7 = ep[7];
      } else {
        n0 = n1 = n2 = n3 = n4 = n5 = n6 = n7 = make_float4(0.f, 0.f, 0.f, 0.f);
      }

      float2* eput = &edge[w][64 + c0];   // my publish slots (write-once)

#define STEP(kk, GK, NE, ND)                                                   \
      {                                                                        \
        const int d = d0 + (kk);                                               \
        const int c = c0 + (kk);                                               \
        const bool valid = ((unsigned)c) < 512u;                               \
        float ddL = (GK) * NL2E;                                               \
        ddL = valid ? ddL : 0.f;                                               \
        float sE = lane_shr1(eSelf);                                           \
        float sD = lane_shr1(dSelfL);                                          \
        sE = l0 ? (NE) : sE;                                                   \
        sD = l0 ? (ND) : sD;                                                   \
        const float e0 = eN2, e1 = sE, e2 = eSelf;                             \
        const float sum = (e0 + e2) + e1;                                      \
        const float inv = __builtin_amdgcn_rcpf(sum);                          \
        const float numL = fmaf(e0, dN2L, fmaf(e1, sD, e2 * dSelfL));          \
        const float rr = fmaf(inv, numL, ddL);                                 \
        float newE = __builtin_amdgcn_exp2f(rr);                               \
        newE = valid ? newE : 0.f;                                             \
        if (d == NM && t == N - 1) {                                           \
          out[b] = rr * NLN2;                                                  \
          out[BATCH + b] = sgA + inv * (e0 * sg0 + e1 * sg1 + e2 * sg2);       \
        }                                                                      \
        eN2 = e1; dN2L = sD;                                                   \
        eSelf = newE; dSelfL = ddL;                                            \
        eput[kk] = make_float2(newE, ddL);                                     \
      }

      STEP(0,  g0,  n0.x, n0.y)  STEP(1,  g1,  n0.z, n0.w)
      STEP(2,  g2,  n1.x, n1.y)  STEP(3,  g3,  n1.z, n1.w)
      STEP(4,  g4,  n2.x, n2.y)  STEP(5,  g5,  n2.z, n2.w)
      STEP(6,  g6,  n3.x, n3.y)  STEP(7,  g7,  n3.z, n3.w)
      STEP(8,  g8,  n4.x, n4.y)  STEP(9,  g9,  n4.z, n4.w)
      STEP(10, g10, n5.x, n5.y)  STEP(11, g11, n5.z, n5.w)
      STEP(12, g12, n6.x, n6.y)  STEP(13, g13, n6.z, n6.w)
      STEP(14, g14, n7.x, n7.y)  STEP(15, g15, n7.z, n7.w)
#undef STEP
    }
    __syncthreads();
  }
}

extern "C" void kernel_launch(void* const* d_in, const int* in_sizes, int n_in,
                              void* d_out, int out_size, void* d_ws, size_t ws_size,
                              hipStream_t stream) {
  const float* D   = (const float*)d_in[0];
  const float* Sig = (const float*)d_in[1];
  float* out = (float*)d_out;
  softdtw_fwd<<<dim3(BATCH), dim3(512), 0, stream>>>(D, Sig, out);
}